// Round 2
// baseline (44.429 us; speedup 1.0000x reference)
//
#include <hip/hip_runtime.h>

// Box filter 1024x1024 constant kernel, reflect pad (pl=pt=511, pr=pb=512).
// Separable. Horizontal: per-row prefix-sum windows (hpass).
// Vertical: out[oy] needs column prefixes P[r] at <=4 rows; for a 64-row
// output band those r form two contiguous 64-row windows -> scan them
// directly from global (coalesced) using band partial sums for the base.

static constexpr float KC = 2.5652997311834374e-21f;
#define IMG (1024 * 1024)

// ---------------- Pass 1: horizontal window sums (one block per row) -------
__device__ __forceinline__ float hwindow(const float* S, int o) {
    float r = 0.f;
    if (o <= 510) r += S[512 - o] - S[1];                 // left mirror
    const int b0 = o > 511 ? o - 511 : 0;                 // main
    const int b1 = o + 513 < 1024 ? o + 513 : 1024;
    r += S[b1] - S[b0];
    if (o >= 512) r += S[1023] - S[1534 - o];             // right mirror
    return r;
}

__global__ __launch_bounds__(256) void hpass_kernel(const float* __restrict__ x,
                                                    float* __restrict__ T) {
    __shared__ float S[1025];
    __shared__ float wtot[4];
    const int t = threadIdx.x;
    const size_t rowbase = (size_t)blockIdx.x * 1024;
    const float4 v = reinterpret_cast<const float4*>(x + rowbase)[t];
    const float p0 = v.x, p1 = p0 + v.y, p2 = p1 + v.z, p3 = p2 + v.w;
    const int lane = t & 63, wave = t >> 6;
    float inc = p3;
    #pragma unroll
    for (int off = 1; off < 64; off <<= 1) {
        float n = __shfl_up(inc, off);
        if (lane >= off) inc += n;
    }
    if (lane == 63) wtot[wave] = inc;
    __syncthreads();
    float woff = 0.f;
    for (int w = 0; w < wave; ++w) woff += wtot[w];
    const float excl = woff + inc - p3;
    S[4 * t + 0] = excl;
    S[4 * t + 1] = excl + p0;
    S[4 * t + 2] = excl + p1;
    S[4 * t + 3] = excl + p2;
    if (t == 255) S[1024] = excl + p3;
    __syncthreads();
    float4 o;
    const int ox = 4 * t;
    o.x = hwindow(S, ox + 0);
    o.y = hwindow(S, ox + 1);
    o.z = hwindow(S, ox + 2);
    o.w = hwindow(S, ox + 3);
    reinterpret_cast<float4*>(T + rowbase)[t] = o;
}

// ---------------- Pass 2a: 16-row band partial column sums -----------------
// grid 1536: band = (ch*64 + k), 4 strips of 256 cols
__global__ __launch_bounds__(256) void bsum_kernel(const float* __restrict__ T,
                                                   float* __restrict__ B16) {
    const int b = blockIdx.x;
    const int strip = b & 3, band = b >> 2;
    const int c = strip * 256 + threadIdx.x;
    const float* p = T + (size_t)band * (16 * 1024) + c;
    float s = 0.f;
    #pragma unroll
    for (int r = 0; r < 16; ++r) s += p[(size_t)r * 1024];
    B16[(size_t)band * 1024 + c] = s;
}

// ---------------- Pass 2b: prefix over band sums (k in [0,64]) -------------
__global__ __launch_bounds__(256) void bprefix_kernel(const float* __restrict__ B16,
                                                      float* __restrict__ BP) {
    const int b = blockIdx.x;                 // 24 = 6ch * 4 strips
    const int ch = b >> 2;
    const int c = (b & 3) * 256 + threadIdx.x;
    const float* src = B16 + (size_t)ch * 64 * 1024 + c;
    float* dst = BP + (size_t)ch * 65 * 1024 + c;
    float run = 0.f;
    #pragma unroll 8
    for (int k = 0; k < 64; ++k) { dst[(size_t)k * 1024] = run; run += src[(size_t)k * 1024]; }
    dst[(size_t)64 * 1024] = run;
}

// ---------------- Pass 3: vertical windows -> output -----------------------
// grid 768: ch(6) x band(16, 64 out rows) x strip(8, 128 cols)
__global__ __launch_bounds__(256) void vwin_kernel(const float* __restrict__ T,
                                                   const float* __restrict__ BP,
                                                   float* __restrict__ out) {
    __shared__ float W1[64][128];
    __shared__ float W2[64][128];
    const int t = threadIdx.x;
    const int b = blockIdx.x;
    const int strip = b & 7, band = (b >> 3) & 15, ch = b >> 7;
    const int O = band * 64, C = strip * 128;
    const float* Tc = T + (size_t)ch * IMG;
    const float* BPc = BP + (size_t)ch * 65 * 1024;
    const int half = t >> 7, c = t & 127, gc = C + c;
    const int oc = c;
    float* ob = out + (size_t)ch * IMG + (size_t)O * 1024 + C;

    if (O <= 448) {
        if (half == 0) {
            // P[449-O+i], i=0..63  (r1 = 512-oy, index 63-ly)
            float run = BPc[(size_t)((448 - O) >> 4) * 1024 + gc];
            const float* p = Tc + (size_t)(448 - O) * 1024 + gc;
            #pragma unroll 8
            for (int i = 0; i < 64; ++i) { run += p[(size_t)i * 1024]; W1[i][c] = run; }
        } else {
            // P[O+513+i], i=0..63  (r2 = oy+513, index ly)
            float run = BPc[(size_t)((O + 512) >> 4) * 1024 + gc];
            const float* p = Tc + (size_t)(O + 512) * 1024 + gc;
            #pragma unroll 8
            for (int i = 0; i < 64; ++i) { run += p[(size_t)i * 1024]; W2[i][c] = run; }
        }
        __syncthreads();
        const float P1 = Tc[C + oc];          // P[1] = T row 0
        #pragma unroll
        for (int it = 0; it < 32; ++it) {
            const int ly = (t >> 7) + it * 2;
            float v = W2[ly][oc];
            if (O + ly != 511) v += W1[63 - ly][oc] - P1;
            ob[(size_t)ly * 1024 + oc] = KC * v;
        }
    } else {
        if (half == 0) {
            // P[O-511+i], i=0..63  (r = oy-511, index ly)
            float run = BPc[(size_t)((O - 512) >> 4) * 1024 + gc];
            const float* p = Tc + (size_t)(O - 512) * 1024 + gc;
            #pragma unroll 8
            for (int i = 0; i < 64; ++i) { run += p[(size_t)i * 1024]; W1[i][c] = run; }
        } else {
            // P[1471-O+i], i=0..63  (r = 1534-oy, index 63-ly); base at 1456-O
            float run = BPc[(size_t)((1456 - O) >> 4) * 1024 + gc];
            const float* p = Tc + (size_t)(1456 - O) * 1024 + gc;
            #pragma unroll 2
            for (int j = 0; j < 14; ++j) run += p[(size_t)j * 1024];
            #pragma unroll 8
            for (int i = 0; i < 64; ++i) { run += p[(size_t)(14 + i) * 1024]; W2[i][c] = run; }
        }
        __syncthreads();
        const float Ptot = BPc[(size_t)64 * 1024 + C + oc];
        const float P1023 = Ptot - Tc[(size_t)1023 * 1024 + C + oc];
        #pragma unroll
        for (int it = 0; it < 32; ++it) {
            const int ly = (t >> 7) + it * 2;
            const float v = (Ptot - W1[ly][oc]) + (P1023 - W2[63 - ly][oc]);
            ob[(size_t)ly * 1024 + oc] = KC * v;
        }
    }
}

extern "C" void kernel_launch(void* const* d_in, const int* in_sizes, int n_in,
                              void* d_out, int out_size, void* d_ws, size_t ws_size,
                              hipStream_t stream) {
    const float* x = (const float*)d_in[2];
    float* out = (float*)d_out;
    float* T = (float*)d_ws;                      // 6*IMG floats
    float* B16 = T + (size_t)6 * IMG;             // 6*64*1024
    float* BP = B16 + (size_t)6 * 64 * 1024;      // 6*65*1024
    hpass_kernel<<<6 * 1024, 256, 0, stream>>>(x, T);
    bsum_kernel<<<1536, 256, 0, stream>>>(T, B16);
    bprefix_kernel<<<24, 256, 0, stream>>>(B16, BP);
    vwin_kernel<<<768, 256, 0, stream>>>(T, BP, out);
}